// Round 1
// baseline (4679.972 us; speedup 1.0000x reference)
//
#include <hip/hip_runtime.h>
#include <math.h>

// Problem constants
#define BB 16
#define SS 256
#define TT 256
#define EE 64
#define HH 128      // encoder hidden
#define VV 32000
#define DH 256      // decoder hidden = 2H

__device__ __forceinline__ float sigmf_(float x) { return 1.0f / (1.0f + expf(-x)); }

// ---------------- init: zero sync flags (ws is poisoned 0xAA each launch) ----------
__global__ void k_init(int* flags) { flags[threadIdx.x] = 0; }

// ---------------- embedding gather ----------------
__global__ __launch_bounds__(256) void k_embed(const int* __restrict__ enc_ids,
    const int* __restrict__ dec_ids, const float* __restrict__ emb,
    float* __restrict__ src_emb, float* __restrict__ tgt_emb)
{
    int i = blockIdx.x * 256 + threadIdx.x;   // one float4 per thread, 65536 total
    int row = i >> 4, c4 = i & 15;
    ((float4*)src_emb)[i] = ((const float4*)(emb + (size_t)enc_ids[row] * EE))[c4];
    ((float4*)tgt_emb)[i] = ((const float4*)(emb + (size_t)dec_ids[row] * EE))[c4];
}

// ---------------- generic NT GEMM: C[M,N] = A[M,K] @ B[N,K(ldb)]^T + bias --------
// 128x128 tile, BK=8, 256 threads, 8x8 microtile. All shapes here divide evenly.
__global__ __launch_bounds__(256) void k_gemm(const float* __restrict__ A,
    const float* __restrict__ Bw, const float* __restrict__ bias,
    float* __restrict__ C, int M, int N, int K, int ldb)
{
    __shared__ float As[8][128];
    __shared__ float Bs[8][128];
    const int tid = threadIdx.x;
    const int bm = blockIdx.y * 128, bn = blockIdx.x * 128;
    const int ti = tid >> 4, tj = tid & 15;
    const int lr = tid >> 1, lk = (tid & 1) * 4;
    float acc[8][8] = {};
    for (int k0 = 0; k0 < K; k0 += 8) {
        float4 av = *(const float4*)&A[(size_t)(bm + lr) * K + k0 + lk];
        float4 bv = *(const float4*)&Bw[(size_t)(bn + lr) * ldb + k0 + lk];
        __syncthreads();
        As[lk+0][lr] = av.x; As[lk+1][lr] = av.y; As[lk+2][lr] = av.z; As[lk+3][lr] = av.w;
        Bs[lk+0][lr] = bv.x; Bs[lk+1][lr] = bv.y; Bs[lk+2][lr] = bv.z; Bs[lk+3][lr] = bv.w;
        __syncthreads();
        #pragma unroll
        for (int kk = 0; kk < 8; ++kk) {
            const float4 a0 = *(const float4*)&As[kk][ti*8];
            const float4 a1 = *(const float4*)&As[kk][ti*8+4];
            const float4 b0 = *(const float4*)&Bs[kk][tj*8];
            const float4 b1 = *(const float4*)&Bs[kk][tj*8+4];
            float av8[8] = {a0.x,a0.y,a0.z,a0.w,a1.x,a1.y,a1.z,a1.w};
            float bv8[8] = {b0.x,b0.y,b0.z,b0.w,b1.x,b1.y,b1.z,b1.w};
            #pragma unroll
            for (int i2 = 0; i2 < 8; ++i2)
                #pragma unroll
                for (int j2 = 0; j2 < 8; ++j2)
                    acc[i2][j2] = fmaf(av8[i2], bv8[j2], acc[i2][j2]);
        }
    }
    float bb[8];
    #pragma unroll
    for (int j2 = 0; j2 < 8; ++j2) bb[j2] = bias ? bias[bn + tj*8 + j2] : 0.f;
    #pragma unroll
    for (int i2 = 0; i2 < 8; ++i2) {
        const size_t row = bm + ti*8 + i2;
        float4 o0, o1;
        o0.x = acc[i2][0]+bb[0]; o0.y = acc[i2][1]+bb[1];
        o0.z = acc[i2][2]+bb[2]; o0.w = acc[i2][3]+bb[3];
        o1.x = acc[i2][4]+bb[4]; o1.y = acc[i2][5]+bb[5];
        o1.z = acc[i2][6]+bb[6]; o1.w = acc[i2][7]+bb[7];
        *(float4*)&C[row * (size_t)N + bn + tj*8]     = o0;
        *(float4*)&C[row * (size_t)N + bn + tj*8 + 4] = o1;
    }
}

// ---------------- Wc = dec_Wih @ attn_W[:,64:]  (NN, small) ----------------
__global__ __launch_bounds__(256) void k_wc(const float* __restrict__ dec_Wih,
    const float* __restrict__ attn_W, float* __restrict__ Wc)
{
    const int r = blockIdx.x, d = threadIdx.x;
    __shared__ float wr[DH];
    wr[d] = dec_Wih[(size_t)r * DH + d];
    __syncthreads();
    float acc = 0.f;
    for (int j = 0; j < DH; ++j)
        acc = fmaf(wr[j], attn_W[(size_t)j * (EE + DH) + EE + d], acc);
    Wc[(size_t)r * DH + d] = acc;
}

// ---------------- encoder recurrence: 32 blocks = (dir, b), no inter-block sync --
// Whh row j lives in thread j's registers (128 VGPR); h/c in LDS; x-part from GEMM.
__global__ __launch_bounds__(512) void k_enc(const float* __restrict__ Xf,
    const float* __restrict__ Xb, const float* __restrict__ WhhF,
    const float* __restrict__ WhhB, float* __restrict__ enc_out,
    float* __restrict__ h0, float* __restrict__ c0)
{
    const int dir = blockIdx.x & 1, b = blockIdx.x >> 1;
    const float* X   = dir ? Xb : Xf;
    const float* Whh = dir ? WhhB : WhhF;
    const int j = threadIdx.x;
    float w[HH];
    #pragma unroll
    for (int kk = 0; kk < HH; kk += 4) {
        float4 v = *(const float4*)&Whh[(size_t)j * HH + kk];
        w[kk] = v.x; w[kk+1] = v.y; w[kk+2] = v.z; w[kk+3] = v.w;
    }
    __shared__ float h_l[HH], c_l[HH], g_l[4*HH];
    if (j < HH) { h_l[j] = 0.f; c_l[j] = 0.f; }
    __syncthreads();
    float xv = X[((size_t)b * SS + (dir ? SS-1 : 0)) * 512 + j];  // prefetch t=0
    for (int t = 0; t < SS; ++t) {
        const int posn = dir ? (SS-2 - t) : (t+1);
        float xnext = (t+1 < SS) ? X[((size_t)b * SS + posn) * 512 + j] : 0.f;
        float acc = 0.f;
        #pragma unroll
        for (int kk = 0; kk < HH; kk += 4) {
            float4 hv = *(const float4*)&h_l[kk];    // same addr all lanes: LDS broadcast
            acc = fmaf(hv.x, w[kk],   acc);
            acc = fmaf(hv.y, w[kk+1], acc);
            acc = fmaf(hv.z, w[kk+2], acc);
            acc = fmaf(hv.w, w[kk+3], acc);
        }
        g_l[j] = acc + xv;
        __syncthreads();
        if (j < HH) {
            const int pos = dir ? (SS-1 - t) : t;
            float ig = sigmf_(g_l[j]);
            float fg = sigmf_(g_l[HH + j]);
            float gg = tanhf(g_l[2*HH + j]);
            float og = sigmf_(g_l[3*HH + j]);
            float cn = fmaf(fg, c_l[j], ig * gg);
            float hn = og * tanhf(cn);
            c_l[j] = cn; h_l[j] = hn;
            enc_out[((size_t)b * SS + pos) * DH + dir * HH + j] = hn;
        }
        __syncthreads();
        xv = xnext;
    }
    if (j < HH) {
        h0[b * DH + dir * HH + j] = h_l[j];
        c0[b * DH + dir * HH + j] = c_l[j];
    }
}

// ---------------- decoder recurrence ----------------
// 128 blocks = 16 b-groups x 8 gate-blocks. Block (b,k) owns hidden slice
// d in [32k,32k+32) => 128 gate rows; weights [Wc|Whh] slice in registers
// (128 VGPR/thread); enc_out[b, 32k:32k+32, :] in LDS for flash-style attention.
// Per step: 2 device-scope flag hops (h broadcast; ctx-partial combine).
// Parity double-buffering of h_buf/pbuf makes overwrite race-free.
__global__ __launch_bounds__(512) void k_dec(
    const float* __restrict__ enc_out, const float* __restrict__ Wc,
    const float* __restrict__ Whh, const float* __restrict__ Gx,
    const float* __restrict__ h0, const float* __restrict__ c0,
    float* __restrict__ hs, float* __restrict__ h_buf,
    float* __restrict__ pbuf, int* __restrict__ h_flags, int* __restrict__ p_flags)
{
    const int blk = blockIdx.x, b = blk >> 3, k = blk & 7;
    const int tid = threadIdx.x;
    __shared__ float enc_l[32][DH];
    __shared__ float h_l[DH], ctx_l[DH], c_l[32], sc_e[32], gates_l[128], red[64];
    __shared__ float part[128][33];
    __shared__ float sc_part[32][17];

    for (int i = tid; i < 32 * DH / 4; i += 512)
        ((float4*)&enc_l[0][0])[i] =
            ((const float4*)&enc_out[((size_t)b * SS + k * 32) * DH])[i];

    const int r8 = tid >> 5, cc8 = tid & 31;
    float w[8][16];
    #pragma unroll
    for (int rr = 0; rr < 8; ++rr) {
        const int rl = r8 * 8 + rr;
        const int grow = ((rl >> 5) << 8) + k * 32 + (rl & 31);  // global gate row
        const float* wsrc = (cc8 < 16) ? &Wc[(size_t)grow * DH + cc8 * 16]
                                       : &Whh[(size_t)grow * DH + (cc8 - 16) * 16];
        #pragma unroll
        for (int q = 0; q < 16; q += 4) {
            float4 v = *(const float4*)&wsrc[q];
            w[rr][q] = v.x; w[rr][q+1] = v.y; w[rr][q+2] = v.z; w[rr][q+3] = v.w;
        }
    }
    if (tid < 32) c_l[tid] = c0[b * DH + k * 32 + tid];
    __syncthreads();

    for (int t = 0; t < TT; ++t) {
        const int par = t & 1;
        float gxv = 0.f;
        if (tid < 128) {   // prefetch Gx early (hides latency behind the step)
            const int grow = ((tid >> 5) << 8) + k * 32 + (tid & 31);
            gxv = Gx[((size_t)b * TT + t) * 1024 + grow];
        }
        if (t == 0) {
            if (tid < DH) h_l[tid] = h0[b * DH + tid];
        } else {
            if (tid < 8)
                while (__hip_atomic_load(&h_flags[b*8 + tid], __ATOMIC_ACQUIRE,
                                         __HIP_MEMORY_SCOPE_AGENT) < t)
                    __builtin_amdgcn_s_sleep(2);
            __syncthreads();
            if (tid < DH)
                h_l[tid] = __hip_atomic_load(&h_buf[(size_t)par*BB*DH + b*DH + tid],
                                             __ATOMIC_RELAXED, __HIP_MEMORY_SCOPE_AGENT);
        }
        __syncthreads();

        // ---- attention scores on our s-slice ----
        {
            const int ss = tid >> 4, p = tid & 15;
            float a = 0.f;
            #pragma unroll
            for (int q = 0; q < 16; q += 4) {
                float4 ev = *(const float4*)&enc_l[ss][p*16 + q];
                float4 hv = *(const float4*)&h_l[p*16 + q];
                a = fmaf(ev.x, hv.x, a); a = fmaf(ev.y, hv.y, a);
                a = fmaf(ev.z, hv.z, a); a = fmaf(ev.w, hv.w, a);
            }
            sc_part[ss][p] = a;
        }
        __syncthreads();
        if (tid < 32) {
            float s = 0.f;
            #pragma unroll
            for (int p = 0; p < 16; ++p) s += sc_part[tid][p];
            sc_e[tid] = s;
        }
        __syncthreads();
        if (tid == 0) {
            float m = sc_e[0];
            #pragma unroll
            for (int i2 = 1; i2 < 32; ++i2) m = fmaxf(m, sc_e[i2]);
            red[0] = m;
        }
        __syncthreads();
        if (tid < 32) sc_e[tid] = expf(sc_e[tid] - red[0]);
        __syncthreads();

        const size_t pslot = ((size_t)(par * BB + b) * 8 + k) * 258;
        if (tid == 0) {
            float s = 0.f;
            #pragma unroll
            for (int i2 = 0; i2 < 32; ++i2) s += sc_e[i2];
            __hip_atomic_store(&pbuf[pslot+0], red[0], __ATOMIC_RELAXED, __HIP_MEMORY_SCOPE_AGENT);
            __hip_atomic_store(&pbuf[pslot+1], s,      __ATOMIC_RELAXED, __HIP_MEMORY_SCOPE_AGENT);
        }
        if (tid < DH) {   // unnormalized local ctx partial
            float a = 0.f;
            #pragma unroll
            for (int s2 = 0; s2 < 32; ++s2) a = fmaf(sc_e[s2], enc_l[s2][tid], a);
            __hip_atomic_store(&pbuf[pslot+2+tid], a, __ATOMIC_RELAXED, __HIP_MEMORY_SCOPE_AGENT);
        }
        __syncthreads();            // barrier drains vmcnt -> partial stores complete
        if (tid == 0) {
            __threadfence();
            __hip_atomic_store(&p_flags[b*8 + k], t + 1, __ATOMIC_RELEASE, __HIP_MEMORY_SCOPE_AGENT);
        }

        // ---- h-half of gates (overlaps peers' publishes) ----
        if (cc8 >= 16) {
            float a[16];
            const int hb = (cc8 - 16) * 16;
            #pragma unroll
            for (int q = 0; q < 16; q += 4) {
                float4 v = *(const float4*)&h_l[hb + q];
                a[q] = v.x; a[q+1] = v.y; a[q+2] = v.z; a[q+3] = v.w;
            }
            #pragma unroll
            for (int rr = 0; rr < 8; ++rr) {
                float s = 0.f;
                #pragma unroll
                for (int q2 = 0; q2 < 16; ++q2) s = fmaf(w[rr][q2], a[q2], s);
                part[r8*8+rr][cc8] = s;
            }
        }

        // ---- wait for all 8 partials, combine softmax ----
        if (tid < 8)
            while (__hip_atomic_load(&p_flags[b*8 + tid], __ATOMIC_ACQUIRE,
                                     __HIP_MEMORY_SCOPE_AGENT) < t + 1)
                __builtin_amdgcn_s_sleep(2);
        __syncthreads();
        if (tid < 8) {
            const size_t ps = ((size_t)(par * BB + b) * 8 + tid) * 258;
            red[8+tid]  = __hip_atomic_load(&pbuf[ps+0], __ATOMIC_RELAXED, __HIP_MEMORY_SCOPE_AGENT);
            red[16+tid] = __hip_atomic_load(&pbuf[ps+1], __ATOMIC_RELAXED, __HIP_MEMORY_SCOPE_AGENT);
        }
        __syncthreads();
        if (tid == 0) {
            float M = red[8];
            #pragma unroll
            for (int i2 = 1; i2 < 8; ++i2) M = fmaxf(M, red[8+i2]);
            float tot = 0.f;
            #pragma unroll
            for (int i2 = 0; i2 < 8; ++i2) {
                float sc = expf(red[8+i2] - M);
                red[24+i2] = sc;
                tot = fmaf(red[16+i2], sc, tot);
            }
            red[32] = 1.0f / tot;
        }
        __syncthreads();
        if (tid < DH) {
            float a = 0.f;
            #pragma unroll
            for (int k2 = 0; k2 < 8; ++k2) {
                const size_t ps = ((size_t)(par * BB + b) * 8 + k2) * 258;
                float v = __hip_atomic_load(&pbuf[ps+2+tid], __ATOMIC_RELAXED, __HIP_MEMORY_SCOPE_AGENT);
                a = fmaf(red[24+k2], v, a);
            }
            ctx_l[tid] = a * red[32];
        }
        __syncthreads();

        // ---- ctx-half of gates ----
        if (cc8 < 16) {
            float a[16];
            const int cb = cc8 * 16;
            #pragma unroll
            for (int q = 0; q < 16; q += 4) {
                float4 v = *(const float4*)&ctx_l[cb + q];
                a[q] = v.x; a[q+1] = v.y; a[q+2] = v.z; a[q+3] = v.w;
            }
            #pragma unroll
            for (int rr = 0; rr < 8; ++rr) {
                float s = 0.f;
                #pragma unroll
                for (int q2 = 0; q2 < 16; ++q2) s = fmaf(w[rr][q2], a[q2], s);
                part[r8*8+rr][cc8] = s;
            }
        }
        __syncthreads();

        // ---- reduce 32 col-chunks per gate row ----
        if (tid < 128) {
            float s = gxv;
            #pragma unroll
            for (int c2 = 0; c2 < 32; ++c2) s += part[tid][c2];
            gates_l[tid] = s;
        }
        __syncthreads();

        // ---- LSTM cell update on our 32 d's ----
        if (tid < 32) {
            float ig = sigmf_(gates_l[tid]);
            float fg = sigmf_(gates_l[32 + tid]);
            float gg = tanhf(gates_l[64 + tid]);
            float og = sigmf_(gates_l[96 + tid]);
            float cn = fmaf(fg, c_l[tid], ig * gg);
            float hn = og * tanhf(cn);
            c_l[tid] = cn;
            hs[((size_t)b * TT + t) * DH + k * 32 + tid] = hn;
            __hip_atomic_store(&h_buf[(size_t)((t+1)&1)*BB*DH + b*DH + k*32 + tid], hn,
                               __ATOMIC_RELAXED, __HIP_MEMORY_SCOPE_AGENT);
        }
        __syncthreads();
        if (tid == 0) {
            __threadfence();
            __hip_atomic_store(&h_flags[b*8 + k], t + 1, __ATOMIC_RELEASE, __HIP_MEMORY_SCOPE_AGENT);
        }
    }
}

// ---------------- host launch ----------------
extern "C" void kernel_launch(void* const* d_in, const int* in_sizes, int n_in,
                              void* d_out, int out_size, void* d_ws, size_t ws_size,
                              hipStream_t stream)
{
    const int*   encrypt = (const int*)  d_in[0];
    const int*   decrypt = (const int*)  d_in[1];
    const float* emb     = (const float*)d_in[2];
    const float* ef_Wih  = (const float*)d_in[3];
    const float* ef_Whh  = (const float*)d_in[4];
    const float* ef_b    = (const float*)d_in[5];
    const float* eb_Wih  = (const float*)d_in[6];
    const float* eb_Whh  = (const float*)d_in[7];
    const float* eb_b    = (const float*)d_in[8];
    const float* dec_Wih = (const float*)d_in[9];
    const float* dec_Whh = (const float*)d_in[10];
    const float* dec_b   = (const float*)d_in[11];
    const float* attn_W  = (const float*)d_in[12];
    const float* attn_b  = (const float*)d_in[13];
    const float* fc_W    = (const float*)d_in[14];
    const float* fc_b    = (const float*)d_in[15];
    float* out = (float*)d_out;
    (void)in_sizes; (void)n_in; (void)out_size; (void)ws_size;  // ws need ~50 MB

    float* ws = (float*)d_ws;
    size_t off = 0;
    auto carve = [&](size_t n) { float* p = ws + off; off += n; return p; };
    float* src_emb = carve((size_t)BB*SS*EE);
    float* tgt_emb = carve((size_t)BB*TT*EE);
    float* Xf      = carve((size_t)BB*SS*512);
    float* Xb      = carve((size_t)BB*SS*512);
    float* Xdec    = carve((size_t)BB*TT*DH);
    float* Gx      = carve((size_t)BB*TT*1024);
    float* Wc      = carve((size_t)1024*DH);
    float* enc_o   = carve((size_t)BB*SS*DH);
    float* h0      = carve((size_t)BB*DH);
    float* c0      = carve((size_t)BB*DH);
    float* hsb     = carve((size_t)BB*TT*DH);
    float* h_buf   = carve((size_t)2*BB*DH);
    float* pbuf    = carve((size_t)2*BB*8*258);
    int*   flags   = (int*)carve(512);
    int* h_flags = flags;
    int* p_flags = flags + 128;

    k_init<<<1, 256, 0, stream>>>(flags);
    k_embed<<<256, 256, 0, stream>>>(encrypt, decrypt, emb, src_emb, tgt_emb);
    // encoder/decoder input-side GEMMs (bias folded in)
    k_gemm<<<dim3(4,  32), 256, 0, stream>>>(src_emb, ef_Wih, ef_b,  Xf,  BB*SS, 512, EE, EE);
    k_gemm<<<dim3(4,  32), 256, 0, stream>>>(src_emb, eb_Wih, eb_b,  Xb,  BB*SS, 512, EE, EE);
    k_gemm<<<dim3(2,  32), 256, 0, stream>>>(tgt_emb, attn_W, attn_b, Xdec, BB*TT, DH, EE, EE+DH);
    k_enc<<<32, 512, 0, stream>>>(Xf, Xb, ef_Whh, eb_Whh, enc_o, h0, c0);
    k_wc<<<1024, 256, 0, stream>>>(dec_Wih, attn_W, Wc);
    k_gemm<<<dim3(8,  32), 256, 0, stream>>>(Xdec, dec_Wih, dec_b, Gx, BB*TT, 1024, DH, DH);
    k_dec<<<128, 512, 0, stream>>>(enc_o, Wc, dec_Whh, Gx, h0, c0, hsb, h_buf, pbuf, h_flags, p_flags);
    // final vocab projection: the dominant GEMM (67 GFLOP fp32)
    k_gemm<<<dim3(VV/128, 32), 256, 0, stream>>>(hsb, fc_W, fc_b, out, BB*TT, VV, DH, DH);
}

// Round 2
// 2492.490 us; speedup vs baseline: 1.8776x; 1.8776x over previous
//
#include <hip/hip_runtime.h>
#include <math.h>

// Problem constants
#define BB 16
#define SS 256
#define TT 256
#define EE 64
#define HH 128      // encoder hidden
#define VV 32000
#define DH 256      // decoder hidden = 2H

__device__ __forceinline__ float sigmf_(float x) { return 1.0f / (1.0f + expf(-x)); }

__device__ __forceinline__ unsigned long long packf_(unsigned tag, float v) {
    return ((unsigned long long)tag << 32) | (unsigned long long)__float_as_uint(v);
}
#define ATLOAD(p)    __hip_atomic_load((p), __ATOMIC_RELAXED, __HIP_MEMORY_SCOPE_AGENT)
#define ATSTORE(p,v) __hip_atomic_store((p), (v), __ATOMIC_RELAXED, __HIP_MEMORY_SCOPE_AGENT)

// ---------------- embedding gather ----------------
__global__ __launch_bounds__(256) void k_embed(const int* __restrict__ enc_ids,
    const int* __restrict__ dec_ids, const float* __restrict__ emb,
    float* __restrict__ src_emb, float* __restrict__ tgt_emb)
{
    int i = blockIdx.x * 256 + threadIdx.x;   // one float4 per thread, 65536 total
    int row = i >> 4, c4 = i & 15;
    ((float4*)src_emb)[i] = ((const float4*)(emb + (size_t)enc_ids[row] * EE))[c4];
    ((float4*)tgt_emb)[i] = ((const float4*)(emb + (size_t)dec_ids[row] * EE))[c4];
}

// ---------------- generic NT GEMM: C[M,N] = A[M,K] @ B[N,K(ldb)]^T + bias --------
// 128x128 tile, BK=8, 256 threads, 8x8 microtile. Optional batch strides on B,C
// via blockIdx.z (A shared). All shapes here divide evenly.
__global__ __launch_bounds__(256) void k_gemm(const float* __restrict__ A,
    const float* __restrict__ Bw, const float* __restrict__ bias,
    float* __restrict__ C, int M, int N, int K, int ldb, long bsB, long bsC)
{
    __shared__ float As[8][128];
    __shared__ float Bs[8][128];
    const float* Bz = Bw + (size_t)blockIdx.z * bsB;
    float* Cz = C + (size_t)blockIdx.z * bsC;
    const int tid = threadIdx.x;
    const int bm = blockIdx.y * 128, bn = blockIdx.x * 128;
    const int ti = tid >> 4, tj = tid & 15;
    const int lr = tid >> 1, lk = (tid & 1) * 4;
    float acc[8][8] = {};
    for (int k0 = 0; k0 < K; k0 += 8) {
        float4 av = *(const float4*)&A[(size_t)(bm + lr) * K + k0 + lk];
        float4 bv = *(const float4*)&Bz[(size_t)(bn + lr) * ldb + k0 + lk];
        __syncthreads();
        As[lk+0][lr] = av.x; As[lk+1][lr] = av.y; As[lk+2][lr] = av.z; As[lk+3][lr] = av.w;
        Bs[lk+0][lr] = bv.x; Bs[lk+1][lr] = bv.y; Bs[lk+2][lr] = bv.z; Bs[lk+3][lr] = bv.w;
        __syncthreads();
        #pragma unroll
        for (int kk = 0; kk < 8; ++kk) {
            const float4 a0 = *(const float4*)&As[kk][ti*8];
            const float4 a1 = *(const float4*)&As[kk][ti*8+4];
            const float4 b0 = *(const float4*)&Bs[kk][tj*8];
            const float4 b1 = *(const float4*)&Bs[kk][tj*8+4];
            float av8[8] = {a0.x,a0.y,a0.z,a0.w,a1.x,a1.y,a1.z,a1.w};
            float bv8[8] = {b0.x,b0.y,b0.z,b0.w,b1.x,b1.y,b1.z,b1.w};
            #pragma unroll
            for (int i2 = 0; i2 < 8; ++i2)
                #pragma unroll
                for (int j2 = 0; j2 < 8; ++j2)
                    acc[i2][j2] = fmaf(av8[i2], bv8[j2], acc[i2][j2]);
        }
    }
    float bb[8];
    #pragma unroll
    for (int j2 = 0; j2 < 8; ++j2) bb[j2] = bias ? bias[bn + tj*8 + j2] : 0.f;
    #pragma unroll
    for (int i2 = 0; i2 < 8; ++i2) {
        const size_t row = bm + ti*8 + i2;
        float4 o0, o1;
        o0.x = acc[i2][0]+bb[0]; o0.y = acc[i2][1]+bb[1];
        o0.z = acc[i2][2]+bb[2]; o0.w = acc[i2][3]+bb[3];
        o1.x = acc[i2][4]+bb[4]; o1.y = acc[i2][5]+bb[5];
        o1.z = acc[i2][6]+bb[6]; o1.w = acc[i2][7]+bb[7];
        *(float4*)&Cz[row * (size_t)N + bn + tj*8]     = o0;
        *(float4*)&Cz[row * (size_t)N + bn + tj*8 + 4] = o1;
    }
}

// ---------------- Wc = dec_Wih @ attn_W[:,64:]  (NN, small) ----------------
__global__ __launch_bounds__(256) void k_wc(const float* __restrict__ dec_Wih,
    const float* __restrict__ attn_W, float* __restrict__ Wc)
{
    const int r = blockIdx.x, d = threadIdx.x;
    __shared__ float wr[DH];
    wr[d] = dec_Wih[(size_t)r * DH + d];
    __syncthreads();
    float acc = 0.f;
    for (int j = 0; j < DH; ++j)
        acc = fmaf(wr[j], attn_W[(size_t)j * (EE + DH) + EE + d], acc);
    Wc[(size_t)r * DH + d] = acc;
}

// ---------------- encoder recurrence: 32 blocks = (dir, b), no inter-block sync --
__global__ __launch_bounds__(512) void k_enc(const float* __restrict__ Xf,
    const float* __restrict__ Xb, const float* __restrict__ WhhF,
    const float* __restrict__ WhhB, float* __restrict__ enc_out,
    float* __restrict__ h0, float* __restrict__ c0)
{
    const int dir = blockIdx.x & 1, b = blockIdx.x >> 1;
    const float* X   = dir ? Xb : Xf;
    const float* Whh = dir ? WhhB : WhhF;
    const int j = threadIdx.x;
    float w[HH];
    #pragma unroll
    for (int kk = 0; kk < HH; kk += 4) {
        float4 v = *(const float4*)&Whh[(size_t)j * HH + kk];
        w[kk] = v.x; w[kk+1] = v.y; w[kk+2] = v.z; w[kk+3] = v.w;
    }
    __shared__ float h_l[HH], c_l[HH], g_l[4*HH];
    if (j < HH) { h_l[j] = 0.f; c_l[j] = 0.f; }
    __syncthreads();
    float xv = X[((size_t)b * SS + (dir ? SS-1 : 0)) * 512 + j];  // prefetch t=0
    for (int t = 0; t < SS; ++t) {
        const int posn = dir ? (SS-2 - t) : (t+1);
        float xnext = (t+1 < SS) ? X[((size_t)b * SS + posn) * 512 + j] : 0.f;
        float acc = 0.f;
        #pragma unroll
        for (int kk = 0; kk < HH; kk += 4) {
            float4 hv = *(const float4*)&h_l[kk];    // same addr all lanes: LDS broadcast
            acc = fmaf(hv.x, w[kk],   acc);
            acc = fmaf(hv.y, w[kk+1], acc);
            acc = fmaf(hv.z, w[kk+2], acc);
            acc = fmaf(hv.w, w[kk+3], acc);
        }
        g_l[j] = acc + xv;
        __syncthreads();
        if (j < HH) {
            const int pos = dir ? (SS-1 - t) : t;
            float ig = sigmf_(g_l[j]);
            float fg = sigmf_(g_l[HH + j]);
            float gg = tanhf(g_l[2*HH + j]);
            float og = sigmf_(g_l[3*HH + j]);
            float cn = fmaf(fg, c_l[j], ig * gg);
            float hn = og * tanhf(cn);
            c_l[j] = cn; h_l[j] = hn;
            enc_out[((size_t)b * SS + pos) * DH + dir * HH + j] = hn;
        }
        __syncthreads();
        xv = xnext;
    }
    if (j < HH) {
        h0[b * DH + dir * HH + j] = h_l[j];
        c0[b * DH + dir * HH + j] = c_l[j];
    }
}

// ---------------- decoder recurrence (ONE sync hop per step) ----------------
// 128 blocks = (k gate-slice 0..7) x (b 0..15); blockIdx = k*16+b so the 8 peers
// of a batch land on the same XCD (blockIdx%8 == b%8 heuristic).
// Block (b,k): d-slice [32k,32k+32) -> 128 gate rows. Registers hold:
//   Whh slice (64), P slice (64) where P = Wc@enc^T (ctx folded: Wc.ctx = sum_s w_s P[:,s]),
//   enc d-slice (16) for score partials.
// Per step: poll 8 packets {scp[256], h[32]} (tagged, fence-free relaxed 8B atomics),
// replicated softmax from gathered score partials, gates = Gx + Whh.h + P.w_tilde,
// cell update, publish next packet. No acquire/release, no threadfence, no flags.
__global__ __launch_bounds__(512, 2) void k_dec(
    const float* __restrict__ enc_out, const float* __restrict__ P,
    const float* __restrict__ Whh, const float* __restrict__ Gx,
    const float* __restrict__ h0, const float* __restrict__ c0,
    float* __restrict__ hs, unsigned long long* __restrict__ ppack)
{
    const int b = blockIdx.x & 15, k = blockIdx.x >> 4;
    const int tid = threadIdx.x;

    __shared__ float sc_l[256];      // gathered full scores
    __shared__ float sc_self[256];   // our own scp (skip self-roundtrip)
    __shared__ float h_l4[4][68];    // gathered h, padded for conflict-free f4 reads
    __shared__ float w_l4[4][68];    // normalized softmax weights, padded
    __shared__ float gates_l[128];
    __shared__ float h_new[32];
    __shared__ float c_l[32];
    __shared__ float red[8];

    const int r = tid >> 2, q = tid & 3;                 // gate compute role
    const int grow = ((r >> 5) << 8) + k * 32 + (r & 31); // global gate row
    const int s2 = tid >> 1, half = tid & 1;             // scp compute role

    // register tiles
    float wreg[64], preg[64], ereg[16];
    #pragma unroll
    for (int j = 0; j < 64; j += 4) {
        float4 v = *(const float4*)&Whh[(size_t)grow * DH + q * 64 + j];
        wreg[j] = v.x; wreg[j+1] = v.y; wreg[j+2] = v.z; wreg[j+3] = v.w;
        float4 u = *(const float4*)&P[((size_t)b * 1024 + grow) * 256 + q * 64 + j];
        preg[j] = u.x; preg[j+1] = u.y; preg[j+2] = u.z; preg[j+3] = u.w;
    }
    #pragma unroll
    for (int j = 0; j < 16; j += 4) {
        float4 v = *(const float4*)&enc_out[((size_t)b * SS + s2) * DH + k * 32 + half * 16 + j];
        ereg[j] = v.x; ereg[j+1] = v.y; ereg[j+2] = v.z; ereg[j+3] = v.w;
    }
    if (tid < 32) {
        c_l[tid]   = c0[b * DH + k * 32 + tid];
        h_new[tid] = h0[b * DH + k * 32 + tid];
    }
    __syncthreads();

    // packet base: ppack[par][b][j][288]  (288 = 256 scp + 32 h)
    #define PKBASE(par) (ppack + (((size_t)(par) * BB + b) * 8) * 288)

    // ---- publish initial packet (tag 1): scp(0) from h0, and h(0) ----
    {
        const unsigned tag = 1u;
        unsigned long long* wbase = PKBASE(tag & 1);
        float a = 0.f;
        #pragma unroll
        for (int j = 0; j < 16; j += 4) {
            float4 hv = *(const float4*)&h_new[half * 16 + j];
            a = fmaf(ereg[j],   hv.x, a); a = fmaf(ereg[j+1], hv.y, a);
            a = fmaf(ereg[j+2], hv.z, a); a = fmaf(ereg[j+3], hv.w, a);
        }
        a += __shfl_xor(a, 1);
        if (half == 0) {
            sc_self[s2] = a;
            ATSTORE(&wbase[(size_t)k * 288 + s2], packf_(tag, a));
        }
        if (tid < 32) ATSTORE(&wbase[(size_t)k * 288 + 256 + tid], packf_(tag, h_new[tid]));
    }
    __syncthreads();

    for (int t = 0; t < TT; ++t) {
        const unsigned rtag = (unsigned)(t + 1);
        unsigned long long* rbase = PKBASE(rtag & 1);

        // Gx prefetch (consumed in Phase C; latency hidden under poll+softmax)
        float gxv = 0.f;
        if (q == 0) gxv = Gx[((size_t)b * TT + t) * 1024 + grow];

        // ---- Phase A: gather scores (tid<256) and h (tid>=256) ----
        if (tid < 256) {
            unsigned long long pk[8];
            #pragma unroll
            for (int j = 0; j < 8; ++j)
                pk[j] = ATLOAD(&rbase[(size_t)j * 288 + tid]);   // issue all 8
            float acc = 0.f;
            #pragma unroll
            for (int j = 0; j < 8; ++j) {
                if (j == k) { acc += sc_self[tid]; continue; }   // uniform branch
                unsigned long long v = pk[j];
                while ((unsigned)(v >> 32) != rtag) {
                    __builtin_amdgcn_s_sleep(1);
                    v = ATLOAD(&rbase[(size_t)j * 288 + tid]);
                }
                acc += __uint_as_float((unsigned)v);
            }
            sc_l[tid] = acc;
        } else {
            const int hd = tid - 256;
            const int hj = hd >> 5;
            float hv;
            if (hj == k) hv = h_new[hd & 31];
            else {
                unsigned long long v = ATLOAD(&rbase[(size_t)hj * 288 + 256 + (hd & 31)]);
                while ((unsigned)(v >> 32) != rtag) {
                    __builtin_amdgcn_s_sleep(1);
                    v = ATLOAD(&rbase[(size_t)hj * 288 + 256 + (hd & 31)]);
                }
                hv = __uint_as_float((unsigned)v);
            }
            h_l4[hd >> 6][hd & 63] = hv;
        }
        __syncthreads();

        // ---- Phase B: softmax over 256 scores (replicated, bit-identical) ----
        float v0 = 0.f;
        if (tid < 256) v0 = sc_l[tid];      // waves 0-3 only; waves 4-7 compute junk, never written
        float m = v0;
        #pragma unroll
        for (int off = 32; off >= 1; off >>= 1) m = fmaxf(m, __shfl_xor(m, off));
        if (tid < 256 && (tid & 63) == 0) red[tid >> 6] = m;
        __syncthreads();
        const float M = fmaxf(fmaxf(red[0], red[1]), fmaxf(red[2], red[3]));
        float e = 0.f;
        if (tid < 256) e = expf(v0 - M);
        float ssum = e;
        #pragma unroll
        for (int off = 32; off >= 1; off >>= 1) ssum += __shfl_xor(ssum, off);
        if (tid < 256 && (tid & 63) == 0) red[4 + (tid >> 6)] = ssum;
        __syncthreads();
        const float inv = 1.0f / (red[4] + red[5] + red[6] + red[7]);
        if (tid < 256) w_l4[tid >> 6][tid & 63] = e * inv;
        __syncthreads();

        // ---- Phase C: gates[r] = Gx + Whh_r . h + P_r . w_tilde ----
        float accW = 0.f, accP = 0.f;
        #pragma unroll
        for (int jj = 0; jj < 16; ++jj) {
            float4 hv = *(const float4*)&h_l4[q][jj * 4];   // banks 4q..: conflict-free
            accW = fmaf(wreg[jj*4],   hv.x, accW);
            accW = fmaf(wreg[jj*4+1], hv.y, accW);
            accW = fmaf(wreg[jj*4+2], hv.z, accW);
            accW = fmaf(wreg[jj*4+3], hv.w, accW);
            float4 wv = *(const float4*)&w_l4[q][jj * 4];
            accP = fmaf(preg[jj*4],   wv.x, accP);
            accP = fmaf(preg[jj*4+1], wv.y, accP);
            accP = fmaf(preg[jj*4+2], wv.z, accP);
            accP = fmaf(preg[jj*4+3], wv.w, accP);
        }
        float p = accW + accP + gxv;   // gxv nonzero only on q==0 lanes
        p += __shfl_xor(p, 1);
        p += __shfl_xor(p, 2);
        if (q == 0) gates_l[r] = p;
        __syncthreads();

        // ---- Phase D: LSTM cell on our 32 dims ----
        if (tid < 32) {
            float ig = sigmf_(gates_l[tid]);
            float fg = sigmf_(gates_l[32 + tid]);
            float gg = tanhf(gates_l[64 + tid]);
            float og = sigmf_(gates_l[96 + tid]);
            float cn = fmaf(fg, c_l[tid], ig * gg);
            float hn = og * tanhf(cn);
            c_l[tid] = cn;
            h_new[tid] = hn;
            hs[((size_t)b * TT + t) * DH + k * 32 + tid] = hn;
        }
        __syncthreads();

        // ---- Phase E: scp(t+1) from h_new, publish packet (tag t+2) ----
        const unsigned wtag = (unsigned)(t + 2);
        unsigned long long* wbase = PKBASE(wtag & 1);
        float a = 0.f;
        #pragma unroll
        for (int j = 0; j < 16; j += 4) {
            float4 hv = *(const float4*)&h_new[half * 16 + j];
            a = fmaf(ereg[j],   hv.x, a); a = fmaf(ereg[j+1], hv.y, a);
            a = fmaf(ereg[j+2], hv.z, a); a = fmaf(ereg[j+3], hv.w, a);
        }
        a += __shfl_xor(a, 1);
        if (half == 0) {
            sc_self[s2] = a;
            ATSTORE(&wbase[(size_t)k * 288 + s2], packf_(wtag, a));
        }
        if (tid < 32) ATSTORE(&wbase[(size_t)k * 288 + 256 + tid], packf_(wtag, h_new[tid]));
        __syncthreads();   // sc_self/h_new stable before next Phase A reads them
    }
    #undef PKBASE
}

// ---------------- host launch ----------------
extern "C" void kernel_launch(void* const* d_in, const int* in_sizes, int n_in,
                              void* d_out, int out_size, void* d_ws, size_t ws_size,
                              hipStream_t stream)
{
    const int*   encrypt = (const int*)  d_in[0];
    const int*   decrypt = (const int*)  d_in[1];
    const float* emb     = (const float*)d_in[2];
    const float* ef_Wih  = (const float*)d_in[3];
    const float* ef_Whh  = (const float*)d_in[4];
    const float* ef_b    = (const float*)d_in[5];
    const float* eb_Wih  = (const float*)d_in[6];
    const float* eb_Whh  = (const float*)d_in[7];
    const float* eb_b    = (const float*)d_in[8];
    const float* dec_Wih = (const float*)d_in[9];
    const float* dec_Whh = (const float*)d_in[10];
    const float* dec_b   = (const float*)d_in[11];
    const float* attn_W  = (const float*)d_in[12];
    const float* attn_b  = (const float*)d_in[13];
    const float* fc_W    = (const float*)d_in[14];
    const float* fc_b    = (const float*)d_in[15];
    float* out = (float*)d_out;
    (void)in_sizes; (void)n_in; (void)out_size; (void)ws_size;  // ws need ~67 MB

    float* ws = (float*)d_ws;
    size_t off = 0;
    auto carve = [&](size_t n) { float* p = ws + off; off += n; return p; };
    float* src_emb = carve((size_t)BB*SS*EE);
    float* tgt_emb = carve((size_t)BB*TT*EE);
    float* Xf      = carve((size_t)BB*SS*512);
    float* Xb      = carve((size_t)BB*SS*512);
    float* Xdec    = carve((size_t)BB*TT*DH);
    float* Gx      = carve((size_t)BB*TT*1024);
    float* Wc      = carve((size_t)1024*DH);
    float* Pm      = carve((size_t)BB*1024*256);   // P = Wc @ enc_b^T per batch
    float* enc_o   = carve((size_t)BB*SS*DH);
    float* h0      = carve((size_t)BB*DH);
    float* c0      = carve((size_t)BB*DH);
    float* hsb     = carve((size_t)BB*TT*DH);
    unsigned long long* ppack = (unsigned long long*)carve((size_t)2*BB*8*288*2);

    k_embed<<<256, 256, 0, stream>>>(encrypt, decrypt, emb, src_emb, tgt_emb);
    // input-side GEMMs (bias folded in)
    k_gemm<<<dim3(4,  32, 1), 256, 0, stream>>>(src_emb, ef_Wih, ef_b,  Xf,  BB*SS, 512, EE, EE, 0, 0);
    k_gemm<<<dim3(4,  32, 1), 256, 0, stream>>>(src_emb, eb_Wih, eb_b,  Xb,  BB*SS, 512, EE, EE, 0, 0);
    k_gemm<<<dim3(2,  32, 1), 256, 0, stream>>>(tgt_emb, attn_W, attn_b, Xdec, BB*TT, DH, EE, EE+DH, 0, 0);
    k_enc<<<32, 512, 0, stream>>>(Xf, Xb, ef_Whh, eb_Whh, enc_o, h0, c0);
    k_wc<<<1024, 256, 0, stream>>>(dec_Wih, attn_W, Wc);
    k_gemm<<<dim3(8,  32, 1), 256, 0, stream>>>(Xdec, dec_Wih, dec_b, Gx, BB*TT, 1024, DH, DH, 0, 0);
    // P[b] = Wc[1024,256] @ enc_b[256,256]^T  (batched over z)
    k_gemm<<<dim3(2, 8, BB), 256, 0, stream>>>(Wc, enc_o, nullptr, Pm, 1024, 256, DH, DH,
                                               (long)SS*DH, (long)1024*256);
    k_dec<<<128, 512, 0, stream>>>(enc_o, Pm, dec_Whh, Gx, h0, c0, hsb, ppack);
    // final vocab projection: the dominant GEMM (67 GFLOP fp32)
    k_gemm<<<dim3(VV/128, 32, 1), 256, 0, stream>>>(hsb, fc_W, fc_b, out, BB*TT, VV, DH, DH, 0, 0);
}